// Round 1
// baseline (400.011 us; speedup 1.0000x reference)
//
#include <hip/hip_runtime.h>
#include <hip/hip_bf16.h>

// Problem constants (fixed by setup_inputs): B=4, N=16384, M=128, C=128, S=512.
// Output layout (float32): pooled (B*M*S*(C+3)) then empty_flag (B*M) as 0.0/1.0.
#define BB   4
#define NN   16384
#define MM   128
#define CC   128
#define SS   512
#define CH   (CC + 3)      // 131
#define BM   (BB * MM)     // 512

// ---------------------------------------------------------------------------
// Kernel A: one wave (64 threads) per box. Scan points in order, ballot-based
// stable compaction of inside-point indices into LDS (first SS entries), then
// wrap-fill idx[k] = idx[k % cnt] so kernel B is a pure gather. Early-exit
// once SS indices are found (exact cnt only matters when cnt < SS).
// Rotation test in double (true value; see numerics note); z-test in float,
// bit-identical to numpy (x*0.5f is exact, rest is plain IEEE add/sub/cmp).
// ---------------------------------------------------------------------------
__global__ __launch_bounds__(64)
void box_sample_kernel(const float* __restrict__ points,  // (B,N,3)
                       const float* __restrict__ boxes,   // (B,M,7)
                       int*  __restrict__ idx_ws,         // (BM,SS)
                       int*  __restrict__ cnt_ws,         // (BM)
                       float* __restrict__ flag_out)      // (BM), tail of d_out
{
    const int box  = blockIdx.x;          // b*MM + m
    const int b    = box >> 7;            // MM = 128
    const int lane = threadIdx.x;         // 0..63

    const float* P  = points + (size_t)b * NN * 3;
    const float* bx = boxes  + (size_t)box * 7;

    const float cx = bx[0], cy = bx[1], cz = bx[2];
    const float dx = bx[3], dy = bx[4], dz = bx[5], rz = bx[6];

    const float  czc = cz + dz * 0.5f;     // geometric center z (exact: dz*0.5 exact)
    const float  hz  = dz * 0.5f;          // exact
    const double ca  = cos(-(double)rz);
    const double sa  = sin(-(double)rz);
    const double hx  = (double)dx * 0.5;
    const double hy  = (double)dy * 0.5;

    __shared__ int s_idx[SS];

    int base = 0;
    for (int i0 = 0; i0 < NN; i0 += 64) {
        const int i = i0 + lane;
        const float px = P[i * 3 + 0];
        const float py = P[i * 3 + 1];
        const float pz = P[i * 3 + 2];

        const double sx = (double)px - (double)cx;
        const double sy = (double)py - (double)cy;
        const float  szf = pz - czc;

        const double lx = sx * ca - sy * sa;
        const double ly = sx * sa + sy * ca;

        const bool inside = (fabs(lx) < hx) && (fabs(ly) < hy) && (fabsf(szf) <= hz);

        const unsigned long long mask = __ballot(inside);
        const int pos = base + __popcll(mask & ((1ull << lane) - 1ull));
        if (inside && pos < SS) s_idx[pos] = i;
        base += __popcll(mask);
        if (base >= SS) break;   // wave-uniform; exact cnt only needed when cnt < SS
    }

    const int cnt = base;
    __syncthreads();

    if (cnt == 0) {
        for (int k = lane; k < SS; k += 64) s_idx[k] = 0;   // safe dummy index
    } else if (cnt < SS) {
        for (int k = cnt + lane; k < SS; k += 64) s_idx[k] = s_idx[k % cnt];
    }
    __syncthreads();

    int* dst = idx_ws + (size_t)box * SS;
    for (int k = lane; k < SS; k += 64) dst[k] = s_idx[k];
    if (lane == 0) {
        cnt_ws[box]   = cnt;
        flag_out[box] = (cnt == 0) ? 1.0f : 0.0f;
    }
}

// ---------------------------------------------------------------------------
// Kernel B: pure gather. One block (256 threads) per box; iterate the box's
// SS*CH output floats; fully coalesced stores, gather loads hit L2/LLC
// (feature tables total 32 MB).
// ---------------------------------------------------------------------------
__global__ __launch_bounds__(256)
void gather_kernel(const float* __restrict__ points,   // (B,N,3)
                   const float* __restrict__ feats,    // (B,N,C)
                   const int*   __restrict__ idx_ws,   // (BM,SS)
                   const int*   __restrict__ cnt_ws,   // (BM)
                   float* __restrict__ out)            // (BM,SS,CH)
{
    const int box = blockIdx.x;
    const int b   = box >> 7;

    const float* P = points + (size_t)b * NN * 3;
    const float* F = feats  + (size_t)b * NN * CC;

    __shared__ int s_idx[SS];
    for (int k = threadIdx.x; k < SS; k += blockDim.x)
        s_idx[k] = idx_ws[(size_t)box * SS + k];
    const float scale = (cnt_ws[box] > 0) ? 1.0f : 0.0f;
    __syncthreads();

    float* dst = out + (size_t)box * SS * CH;
    const int TOT = SS * CH;    // 67072
    for (int t = threadIdx.x; t < TOT; t += blockDim.x) {
        const int k = t / CH;            // constant divisor -> magic multiply
        const int c = t - k * CH;
        const int idx = s_idx[k];
        const float v = (c < 3) ? P[idx * 3 + c] : F[idx * CC + (c - 3)];
        dst[t] = v * scale;
    }
}

extern "C" void kernel_launch(void* const* d_in, const int* in_sizes, int n_in,
                              void* d_out, int out_size, void* d_ws, size_t ws_size,
                              hipStream_t stream) {
    const float* points = (const float*)d_in[0];
    const float* feats  = (const float*)d_in[1];
    const float* boxes  = (const float*)d_in[2];
    // d_in[3] = num_sampled_points, fixed at 512 by setup_inputs.

    int*  idx_ws = (int*)d_ws;                       // BM*SS ints = 1 MiB
    int*  cnt_ws = idx_ws + (size_t)BM * SS;         // BM ints
    float* out      = (float*)d_out;
    float* flag_out = out + (size_t)BM * SS * CH;    // empty_flag as float 0/1

    box_sample_kernel<<<BM, 64, 0, stream>>>(points, boxes, idx_ws, cnt_ws, flag_out);
    gather_kernel<<<BM, 256, 0, stream>>>(points, feats, idx_ws, cnt_ws, out);
}

// Round 2
// 225.376 us; speedup vs baseline: 1.7749x; 1.7749x over previous
//
#include <hip/hip_runtime.h>
#include <hip/hip_bf16.h>

// Problem constants (fixed by setup_inputs): B=4, N=16384, M=128, C=128, S=512.
// Output layout (float32): pooled (B*M*S*(C+3)) then empty_flag (B*M) as 0.0/1.0.
#define BB   4
#define NN   16384
#define MM   128
#define CC   128
#define SS   512
#define CH   (CC + 3)      // 131
#define BM   (BB * MM)     // 512
#define WAVES 4            // waves per box in kernel A
#define CHUNK (NN / WAVES) // 4096 points per wave

// ---------------------------------------------------------------------------
// Kernel A: one block (4 waves) per box. Each wave stably compacts its
// contiguous 4096-point chunk into an LDS segment (first SS entries + count),
// then the block merges segments by prefix offsets (stable: chunks are in
// ascending index order), wrap-fills idx[k]=idx[k%cnt], and writes idx/cnt/flag.
// Early-exit per wave once its own count hits SS (then total>=SS, and the
// exact total is only needed when total<SS). Rotation test in double
// (true value >> fp32 ref error); z-test bit-identical fp32.
// ---------------------------------------------------------------------------
__global__ __launch_bounds__(256)
void box_sample_kernel(const float* __restrict__ points,  // (B,N,3)
                       const float* __restrict__ boxes,   // (B,M,7)
                       int*  __restrict__ idx_ws,         // (BM,SS)
                       int*  __restrict__ cnt_ws,         // (BM)
                       float* __restrict__ flag_out)      // (BM)
{
    const int box  = blockIdx.x;          // b*MM + m
    const int b    = box >> 7;            // MM = 128
    const int lane = threadIdx.x & 63;
    const int w    = threadIdx.x >> 6;    // wave 0..3

    const float* P  = points + (size_t)b * NN * 3;
    const float* bx = boxes  + (size_t)box * 7;

    const float cx = bx[0], cy = bx[1], cz = bx[2];
    const float dx = bx[3], dy = bx[4], dz = bx[5], rz = bx[6];

    const float  czc = cz + dz * 0.5f;     // exact
    const float  hz  = dz * 0.5f;          // exact
    const double ca  = cos(-(double)rz);
    const double sa  = sin(-(double)rz);
    const double hx  = (double)dx * 0.5;
    const double hy  = (double)dy * 0.5;

    __shared__ int s_part[WAVES][SS];
    __shared__ int s_cnt[WAVES];
    __shared__ int s_idx[SS];

    int cnt = 0;
    const int pbase = w * CHUNK;
    for (int i0 = 0; i0 < CHUNK; i0 += 64) {
        const int i = pbase + i0 + lane;
        const float px = P[i * 3 + 0];
        const float py = P[i * 3 + 1];
        const float pz = P[i * 3 + 2];

        const double sx = (double)px - (double)cx;
        const double sy = (double)py - (double)cy;
        const float  szf = pz - czc;

        const double lx = sx * ca - sy * sa;
        const double ly = sx * sa + sy * ca;

        const bool inside = (fabs(lx) < hx) && (fabs(ly) < hy) && (fabsf(szf) <= hz);

        const unsigned long long mask = __ballot(inside);
        const int pos = cnt + __popcll(mask & ((1ull << lane) - 1ull));
        if (inside && pos < SS) s_part[w][pos] = i;
        cnt += __popcll(mask);
        if (cnt >= SS) break;   // wave-uniform; total>=SS from here on
    }
    if (lane == 0) s_cnt[w] = cnt;
    __syncthreads();

    const int c0 = s_cnt[0], c1 = s_cnt[1], c2 = s_cnt[2], c3 = s_cnt[3];
    const int o1 = c0, o2 = c0 + c1, o3 = c0 + c1 + c2;
    const int total = o3 + c3;   // exact iff total < SS (no early exit then)

    // merge segments into the first min(total,SS) slots, stable order
    for (int k = threadIdx.x; k < SS; k += 256) {
        int v = 0;
        if      (k < c0)    v = s_part[0][k];
        else if (k < o2)    v = s_part[1][k - o1];
        else if (k < o3)    v = s_part[2][k - o2];
        else if (k < total) v = s_part[3][k - o3];
        s_idx[k] = v;
    }
    __syncthreads();

    if (total > 0 && total < SS) {
        for (int k = total + threadIdx.x; k < SS; k += 256)
            s_idx[k] = s_idx[k % total];
        __syncthreads();
    }

    int* dst = idx_ws + (size_t)box * SS;
    for (int k = threadIdx.x; k < SS; k += 256) dst[k] = s_idx[k];
    if (threadIdx.x == 0) {
        cnt_ws[box]   = total;
        flag_out[box] = (total == 0) ? 1.0f : 0.0f;
    }
}

// ---------------------------------------------------------------------------
// Kernel B: gather. Grid (512 boxes, 16 chunks of 32 samples); block = 256
// threads = 8 half-waves of 32 lanes. Each half-wave handles 4 samples
// (unrolled, independent -> 4 float4 loads in flight). Features loaded as
// float4 (src 16B-aligned: idx*128 floats), stored as 4 scalars (contiguous
// per half-wave, L2 write-combines). Lanes 0..2 also handle the 3 point xyz.
// ---------------------------------------------------------------------------
__global__ __launch_bounds__(256)
void gather_kernel(const float* __restrict__ points,   // (B,N,3)
                   const float* __restrict__ feats,    // (B,N,C)
                   const int*   __restrict__ idx_ws,   // (BM,SS)
                   const int*   __restrict__ cnt_ws,   // (BM)
                   float* __restrict__ out)            // (BM,SS,CH)
{
    const int box   = blockIdx.x;         // 0..511
    const int chunk = blockIdx.y;         // 0..15
    const int b     = box >> 7;
    const int tid   = threadIdx.x;
    const int hw    = tid >> 5;           // half-wave 0..7
    const int j     = tid & 31;           // lane in half-wave

    __shared__ int   s_idx[32];
    __shared__ float s_scale;
    if (tid < 32) s_idx[tid] = idx_ws[(size_t)box * SS + chunk * 32 + tid];
    if (tid == 0) s_scale = (cnt_ws[box] > 0) ? 1.0f : 0.0f;
    __syncthreads();
    const float scale = s_scale;

    const float4* F4 = (const float4*)(feats + (size_t)b * NN * CC);
    const float*  Pb = points + (size_t)b * NN * 3;
    float* dstbox = out + (size_t)box * SS * CH + (size_t)chunk * 32 * CH;

    #pragma unroll
    for (int s = 0; s < 4; ++s) {
        const int k   = hw + s * 8;       // sample within chunk, 0..31
        const int idx = s_idx[k];
        const float4 v = F4[idx * 32 + j];
        float* d = dstbox + k * CH;
        d[3 + 4 * j + 0] = v.x * scale;
        d[3 + 4 * j + 1] = v.y * scale;
        d[3 + 4 * j + 2] = v.z * scale;
        d[3 + 4 * j + 3] = v.w * scale;
        if (j < 3) d[j] = Pb[idx * 3 + j] * scale;
    }
}

extern "C" void kernel_launch(void* const* d_in, const int* in_sizes, int n_in,
                              void* d_out, int out_size, void* d_ws, size_t ws_size,
                              hipStream_t stream) {
    const float* points = (const float*)d_in[0];
    const float* feats  = (const float*)d_in[1];
    const float* boxes  = (const float*)d_in[2];
    // d_in[3] = num_sampled_points, fixed at 512 by setup_inputs.

    int*  idx_ws = (int*)d_ws;                       // BM*SS ints = 1 MiB
    int*  cnt_ws = idx_ws + (size_t)BM * SS;         // BM ints
    float* out      = (float*)d_out;
    float* flag_out = out + (size_t)BM * SS * CH;    // empty_flag as float 0/1

    box_sample_kernel<<<BM, 256, 0, stream>>>(points, boxes, idx_ws, cnt_ws, flag_out);
    dim3 ggrid(BM, SS / 32);
    gather_kernel<<<ggrid, 256, 0, stream>>>(points, feats, idx_ws, cnt_ws, out);
}

// Round 3
// 197.686 us; speedup vs baseline: 2.0235x; 1.1401x over previous
//
#include <hip/hip_runtime.h>
#include <hip/hip_bf16.h>

// Problem constants (fixed by setup_inputs): B=4, N=16384, M=128, C=128, S=512.
// Output layout (float32): pooled (B*M*S*(C+3)) then empty_flag (B*M) as 0.0/1.0.
#define BB   4
#define NN   16384
#define MM   128
#define CC   128
#define SS   512
#define CH   (CC + 3)      // 131
#define BM   (BB * MM)     // 512
#define WAVES 8            // waves per box in kernel A
#define CHUNK (NN / WAVES) // 2048 points per wave

// ---------------------------------------------------------------------------
// Kernel A: one block (8 waves, 512 thr) per box. Each wave stably compacts
// its contiguous 2048-point chunk into an LDS segment; block merges segments
// by prefix offsets (stable), wrap-fills idx[k]=idx[k%cnt], writes idx/flag.
// No early exit (worthless at 8 chunks) -> clean 4x unroll with loads hoisted.
// Rotation test in double (true value >> fp32 ref roundoff); z-test fp32,
// bit-identical to numpy.
// ---------------------------------------------------------------------------
__global__ __launch_bounds__(512)
void box_sample_kernel(const float* __restrict__ points,  // (B,N,3)
                       const float* __restrict__ boxes,   // (B,M,7)
                       int*  __restrict__ idx_ws,         // (BM,SS)
                       int*  __restrict__ cnt_ws,         // (BM)
                       float* __restrict__ flag_out)      // (BM)
{
    const int box  = blockIdx.x;          // b*MM + m
    const int b    = box >> 7;            // MM = 128
    const int lane = threadIdx.x & 63;
    const int w    = threadIdx.x >> 6;    // wave 0..7

    const float* P  = points + (size_t)b * NN * 3;
    const float* bx = boxes  + (size_t)box * 7;

    const float cx = bx[0], cy = bx[1], cz = bx[2];
    const float dx = bx[3], dy = bx[4], dz = bx[5], rz = bx[6];

    const float  czc = cz + dz * 0.5f;     // exact
    const float  hz  = dz * 0.5f;          // exact
    const double ca  = cos(-(double)rz);
    const double sa  = sin(-(double)rz);
    const double hx  = (double)dx * 0.5;
    const double hy  = (double)dy * 0.5;

    __shared__ int s_part[WAVES][SS];     // 16 KB
    __shared__ int s_cnt[WAVES];
    __shared__ int s_idx[SS];

    int cnt = 0;
    const int pbase = w * CHUNK;
    for (int i0 = 0; i0 < CHUNK; i0 += 256) {     // 8 outer iterations
        float px[4], py[4], pz[4];
        #pragma unroll
        for (int u = 0; u < 4; ++u) {
            const int i = pbase + i0 + u * 64 + lane;
            px[u] = P[i * 3 + 0];
            py[u] = P[i * 3 + 1];
            pz[u] = P[i * 3 + 2];
        }
        #pragma unroll
        for (int u = 0; u < 4; ++u) {
            const double sx = (double)px[u] - (double)cx;
            const double sy = (double)py[u] - (double)cy;
            const float  szf = pz[u] - czc;
            const double lx = sx * ca - sy * sa;
            const double ly = sx * sa + sy * ca;
            const bool inside = (fabs(lx) < hx) && (fabs(ly) < hy) && (fabsf(szf) <= hz);
            const unsigned long long mask = __ballot(inside);
            const int pos = cnt + __popcll(mask & ((1ull << lane) - 1ull));
            if (inside && pos < SS) s_part[w][pos] = pbase + i0 + u * 64 + lane;
            cnt += __popcll(mask);
        }
    }
    if (lane == 0) s_cnt[w] = cnt;
    __syncthreads();

    int c[WAVES], off[WAVES];
    int total = 0;
    #pragma unroll
    for (int q = 0; q < WAVES; ++q) { c[q] = s_cnt[q]; off[q] = total; total += c[q]; }

    // merge segments into first min(total,SS) slots, stable order
    for (int k = threadIdx.x; k < SS; k += 512) {
        int v = 0;
        #pragma unroll
        for (int q = 0; q < WAVES; ++q) {
            const int r = k - off[q];
            if (r >= 0 && r < c[q]) v = s_part[q][r];
        }
        s_idx[k] = v;
    }
    __syncthreads();

    if (total > 0 && total < SS) {
        for (int k = total + threadIdx.x; k < SS; k += 512)
            s_idx[k] = s_idx[k % total];
        __syncthreads();
    }

    int* dst = idx_ws + (size_t)box * SS;
    for (int k = threadIdx.x; k < SS; k += 512) dst[k] = s_idx[k];
    if (threadIdx.x == 0) {
        cnt_ws[box]   = total;
        flag_out[box] = (total == 0) ? 1.0f : 0.0f;
    }
}

// ---------------------------------------------------------------------------
// Kernel B: gather. Grid (512 boxes, 16 chunks of 32 samples); 256 threads.
// Phase 1: float4 gathers from feats (coalesced 512B per half-wave per row)
// staged into an LDS image of the chunk's 4192-float output span (LDS writes
// are lane-stride-4 -> ~8-way bank aliasing, acceptable). Phase 2: the span
// is 16B-aligned (32*131*4 B = 16768, box/chunk offsets multiples of 16) ->
// perfectly coalesced float4 stores.
// ---------------------------------------------------------------------------
__global__ __launch_bounds__(256)
void gather_kernel(const float* __restrict__ points,   // (B,N,3)
                   const float* __restrict__ feats,    // (B,N,C)
                   const int*   __restrict__ idx_ws,   // (BM,SS)
                   const int*   __restrict__ cnt_ws,   // (BM)
                   float* __restrict__ out)            // (BM,SS,CH)
{
    const int box   = blockIdx.x;         // 0..511
    const int chunk = blockIdx.y;         // 0..15
    const int b     = box >> 7;
    const int tid   = threadIdx.x;
    const int hw    = tid >> 5;           // half-wave 0..7
    const int j     = tid & 31;           // lane in half-wave

    __shared__ int   s_idx[32];
    __shared__ float s_scale;
    __shared__ __align__(16) float s_buf[32 * CH];   // 4192 floats = 16768 B

    if (tid < 32) s_idx[tid] = idx_ws[(size_t)box * SS + chunk * 32 + tid];
    if (tid == 0) s_scale = (cnt_ws[box] > 0) ? 1.0f : 0.0f;
    __syncthreads();
    const float scale = s_scale;

    const float4* F4 = (const float4*)(feats + (size_t)b * NN * CC);
    const float*  Pb = points + (size_t)b * NN * 3;

    #pragma unroll
    for (int s = 0; s < 4; ++s) {
        const int k   = hw + s * 8;       // sample within chunk, 0..31
        const int idx = s_idx[k];
        const float4 v = F4[idx * 32 + j];
        const int base = k * CH + 3 + 4 * j;
        s_buf[base + 0] = v.x * scale;
        s_buf[base + 1] = v.y * scale;
        s_buf[base + 2] = v.z * scale;
        s_buf[base + 3] = v.w * scale;
        if (j < 3) s_buf[k * CH + j] = Pb[idx * 3 + j] * scale;
    }
    __syncthreads();

    const float4* src4 = (const float4*)s_buf;
    float4* dst4 = (float4*)(out + (size_t)box * SS * CH + (size_t)chunk * 32 * CH);
    #pragma unroll
    for (int s = 0; s < 4; ++s) dst4[s * 256 + tid] = src4[s * 256 + tid];
    if (tid < 24) dst4[1024 + tid] = src4[1024 + tid];   // 1048 total
}

extern "C" void kernel_launch(void* const* d_in, const int* in_sizes, int n_in,
                              void* d_out, int out_size, void* d_ws, size_t ws_size,
                              hipStream_t stream) {
    const float* points = (const float*)d_in[0];
    const float* feats  = (const float*)d_in[1];
    const float* boxes  = (const float*)d_in[2];
    // d_in[3] = num_sampled_points, fixed at 512 by setup_inputs.

    int*  idx_ws = (int*)d_ws;                       // BM*SS ints = 1 MiB
    int*  cnt_ws = idx_ws + (size_t)BM * SS;         // BM ints
    float* out      = (float*)d_out;
    float* flag_out = out + (size_t)BM * SS * CH;    // empty_flag as float 0/1

    box_sample_kernel<<<BM, 512, 0, stream>>>(points, boxes, idx_ws, cnt_ws, flag_out);
    dim3 ggrid(BM, SS / 32);
    gather_kernel<<<ggrid, 256, 0, stream>>>(points, feats, idx_ws, cnt_ws, out);
}